// Round 14
// baseline (498.085 us; speedup 1.0000x reference)
//
#include <hip/hip_runtime.h>
#include <hip/hip_bf16.h>

typedef __hip_bfloat16 bf16;
typedef float f32x4 __attribute__((ext_vector_type(4)));
typedef short bf16x8 __attribute__((ext_vector_type(8)));
typedef short short4v __attribute__((ext_vector_type(4)));
typedef unsigned int u32;

#define NTOK 100352   // 32*56*56 tokens = 2048 windows * 49
#define CC 192
#define HIDN 768

__device__ __forceinline__ float b2f(unsigned short u) {
    union { unsigned int u32v; float f; } x; x.u32v = ((unsigned int)u) << 16; return x.f;
}
__device__ __forceinline__ unsigned short f2b(float f) {
    union { float f; unsigned int u; } x; x.f = f;
    unsigned int r = x.u + 0x7FFF + ((x.u >> 16) & 1);
    return (unsigned short)(r >> 16);
}
// sigmoid-form gelu (validated R13: absmax unchanged at 0.03125)
__device__ __forceinline__ float gelu_f(float x) {
    return x / (1.0f + __expf(-1.702f * x));
}

typedef __attribute__((address_space(1))) const unsigned char gas_u8;
typedef __attribute__((address_space(3))) unsigned char las_u8;
__device__ __forceinline__ void gload_lds16(const void* g, void* l) {
    __builtin_amdgcn_global_load_lds((gas_u8*)g, (las_u8*)l, 16, 0, 0);
}

// ---------------- weight prep: fp32 src [R][C] -> bf16 dst[c*R + r] ----------------
__global__ void transpose_k(const float* __restrict__ src, bf16* __restrict__ dst, int R, int C) {
    int idx = blockIdx.x * 256 + threadIdx.x;
    if (idx >= R * C) return;
    int r = idx / C, c = idx % C;
    dst[(size_t)c * R + r] = __float2bfloat16(src[idx]);
}

// ---------------- biasmask table: [cls][head][mt][nt][lane][reg] f32, acc-frag layout. ----------------
__global__ void bm_k(const float* __restrict__ btab, float* __restrict__ bm) {
    int idx = blockIdx.x * 256 + threadIdx.x;           // 4*6*16*256 = 98304
    if (idx >= 98304) return;
    int reg = idx & 3, lane = (idx >> 2) & 63, tile = (idx >> 8) & 15;
    int rest = idx >> 12, h = rest % 6, cls = rest / 6;
    int mt = tile >> 2, nt = tile & 3;
    int kk = mt * 16 + (lane >> 4) * 4 + reg;
    int q  = nt * 16 + (lane & 15);
    float v;
    if (kk >= 49 || q >= 49) v = -1e9f;
    else {
        int i1 = q / 7, j1 = q % 7, i2 = kk / 7, j2 = kk % 7;
        v = btab[((i1 - i2 + 6) * 13 + (j1 - j2 + 6)) * 6 + h];
        int hb7 = cls >> 1, wb7 = cls & 1;
        int r1 = (hb7 ? (i1 < 4 ? 1 : 2) : 0) * 3 + (wb7 ? (j1 < 4 ? 1 : 2) : 0);
        int r2 = (hb7 ? (i2 < 4 ? 1 : 2) : 0) * 3 + (wb7 ? (j2 < 4 ? 1 : 2) : 0);
        if (r1 != r2) v -= 100.0f;
    }
    bm[idx] = v;
}

// ---------------- LayerNorm (wave per token) -> bf16 rows. ----------------
template<bool GATHER>
__global__ __launch_bounds__(256) void ln_k(const float* __restrict__ src,
                                            const float* __restrict__ gamma,
                                            const float* __restrict__ beta,
                                            bf16* __restrict__ dst) {
    int wave = threadIdx.x >> 6, lane = threadIdx.x & 63;
    int t = blockIdx.x * 4 + wave;           // output token index
    size_t srow;
    if (GATHER) {
        int w = t / 49, n = t % 49;
        int b = w >> 6, wl = w & 63, hb = wl >> 3, wb = wl & 7;
        int i = n / 7, j = n % 7;
        int sh = hb * 7 + i + 3; if (sh >= 56) sh -= 56;   // roll(-3): src=(dst+3)%56
        int sw = wb * 7 + j + 3; if (sw >= 56) sw -= 56;
        srow = ((size_t)(b * 56 + sh) * 56 + sw) * CC;
    } else {
        srow = (size_t)t * CC;
    }
    float v[4];
    int c = lane * 4;
    float sum = 0.f, sq = 0.f;
    if (lane < 48) {
        f32x4 d = *(const f32x4*)(src + srow + c);
        #pragma unroll
        for (int q = 0; q < 4; ++q) { v[q] = d[q]; sum += v[q]; sq += v[q] * v[q]; }
    }
    #pragma unroll
    for (int off = 1; off < 64; off <<= 1) { sum += __shfl_xor(sum, off); sq += __shfl_xor(sq, off); }
    float mu = sum * (1.0f / 192.0f);
    float var = sq * (1.0f / 192.0f) - mu * mu;
    float rstd = rsqrtf(var + 1e-5f);
    if (lane < 48) {
        f32x4 gg = *(const f32x4*)(gamma + c);
        f32x4 bb = *(const f32x4*)(beta + c);
        short4v o;
        #pragma unroll
        for (int q = 0; q < 4; ++q) {
            float val = (v[q] - mu) * rstd * gg[q] + bb[q];
            o[q] = (short)f2b(val);
        }
        *(short4v*)(dst + (size_t)t * CC + c) = o;
    }
}

// ======== shared epilogue (swapped-operand D-layout: lane&15 = output row,
// (lane>>4)*4 + reg = 4 consecutive output cols -> vector stores) ========
template<int EPI>
__device__ __forceinline__ void epilogue(
    f32x4 (&acc)[4][2], int tm0, int tn0, int w0, int w1, int lane, int N,
    const float* __restrict__ bias, bf16* __restrict__ outb, float* __restrict__ outf,
    const float* __restrict__ xres, const float* __restrict__ yin)
{
    const int r16 = lane & 15, q4 = (lane >> 4) * 4;
    #pragma unroll
    for (int mt = 0; mt < 4; ++mt) {
        int mm = tm0 + w1 * 64 + mt * 16 + r16;
        size_t rowbase;
        if (EPI == 1) {
            int ww = mm / 49, nn = mm % 49;
            int b_ = ww >> 6, wl = ww & 63, hb = wl >> 3, wb = wl & 7;
            int i = nn / 7, j = nn % 7;
            int oh = hb * 7 + i + 3; if (oh >= 56) oh -= 56;   // roll(+3)
            int ow = wb * 7 + j + 3; if (ow >= 56) ow -= 56;
            rowbase = ((size_t)(b_ * 56 + oh) * 56 + ow) * CC;
        } else {
            rowbase = (size_t)mm * N;
        }
        #pragma unroll
        for (int nt = 0; nt < 2; ++nt) {
            int col = tn0 + w0 * 32 + nt * 16 + q4;
            f32x4 bv = *(const f32x4*)(bias + col);
            f32x4 v;
            #pragma unroll
            for (int r = 0; r < 4; ++r) v[r] = acc[mt][nt][r] + bv[r];
            if (EPI == 1) {
                f32x4 xr = *(const f32x4*)(xres + rowbase + col);
                #pragma unroll
                for (int r = 0; r < 4; ++r) v[r] += xr[r];
                *(f32x4*)(outf + rowbase + col) = v;
            } else {
                size_t ob = ((size_t)(col >> 5) * NTOK + mm) * 32 + (col & 31);
                short4v o;
                #pragma unroll
                for (int r = 0; r < 4; ++r) o[r] = (short)f2b(v[r]);
                *(short4v*)(outb + ob) = o;
            }
        }
    }
}

// ---------------- K=192 GEMM (qkv EPI4, proj EPI1): A-only LDS single-shot, W prefetched
// to registers (R13-validated structure). ----------------
template<int EPI, int NX>
__global__ __launch_bounds__(256) void gemm_ss(
    const bf16* __restrict__ X, const bf16* __restrict__ WT,
    const float* __restrict__ bias, int N,
    bf16* __restrict__ outb, float* __restrict__ outf,
    const float* __restrict__ xres, const float* __restrict__ yin)
{
    constexpr int K = 192;
    __shared__ bf16 As[3][128 * 64];   // 16 KiB per K-tile
    const int tid = threadIdx.x;
    const int w = tid >> 6, lane = tid & 63;
    const int w0 = w & 1, w1 = w >> 1;

    const u32 nwg = NX * 784;
    u32 bid = blockIdx.y * NX + blockIdx.x;
    bid = (bid & 7) * (nwg >> 3) + (bid >> 3);          // bijective (nwg%8==0)
    const int tn0 = (int)(bid % NX) * 64;
    const int tm0 = (int)(bid / NX) * 128;

    const int r16 = lane & 15, g8 = (lane >> 4) * 8;

    // --- W fragments -> registers (issued first; ready by the barrier) ---
    const bf16* gW0 = WT + (size_t)(tn0 + w0 * 32 + r16) * K + g8;
    const bf16* gW1 = gW0 + 16 * K;
    bf16x8 wreg[3][2][2];
    #pragma unroll
    for (int t = 0; t < 3; ++t)
        #pragma unroll
        for (int k32 = 0; k32 < 2; ++k32) {
            wreg[t][k32][0] = *(const bf16x8*)(gW0 + t * 64 + k32 * 32);
            wreg[t][k32][1] = *(const bf16x8*)(gW1 + t * 64 + k32 * 32);
        }

    // --- A staging: all 3 K-tiles, one shot ---
    const bf16* gA[4];
    #pragma unroll
    for (int j = 0; j < 4; ++j) {
        int c = (w * 4 + j) * 64 + lane;
        int l = c ^ ((c >> 3) & 7);          // inverse swizzle on source
        gA[j] = X + (size_t)(tm0 + (c >> 3)) * K + (l & 7) * 8;
    }
    #pragma unroll
    for (int t = 0; t < 3; ++t)
        #pragma unroll
        for (int j = 0; j < 4; ++j)
            gload_lds16(gA[j] + (t << 6), (char*)&As[t][0] + (size_t)(w * 4 + j) * 1024);
    __syncthreads();                          // the ONLY barrier

    f32x4 acc[4][2] = {};
    #pragma unroll
    for (int t = 0; t < 3; ++t) {
        const char* ab = (const char*)&As[t][0];
        #pragma unroll
        for (int k32 = 0; k32 < 2; ++k32) {
            int kcolb = k32 * 64 + g8 * 2;
            bf16x8 xf[4];
            #pragma unroll
            for (int m = 0; m < 4; ++m) {
                int row = w1 * 64 + m * 16 + r16;
                int byte = row * 128 + kcolb;
                xf[m] = *(const bf16x8*)(ab + (byte ^ ((row & 7) << 4)));
            }
            #pragma unroll
            for (int m = 0; m < 4; ++m)
                #pragma unroll
                for (int n = 0; n < 2; ++n)
                    acc[m][n] = __builtin_amdgcn_mfma_f32_16x16x32_bf16(wreg[t][k32][n], xf[m], acc[m][n], 0, 0, 0);
        }
    }
    epilogue<EPI>(acc, tm0, tn0, w0, w1, lane, N, bias, outb, outf, xres, yin);
}

// ---------------- FUSED MLP: y += gelu(m @ W1 + b1) @ W2 + b2  (per 128-row block).
// X (m-tile) staged once in LDS; 6 slices of 128 hid-cols: phase A = fc1 slice (W1 frags
// from L2), gelu, pack bf16 -> swizzled LDS Hs; phase B accumulates y-acc via fc2 slice
// (W2 frags from L2). acc2[4][6] persists (wave = 64 m-rows x 96 y-cols). LDS 80KB. ----------------
__global__ __launch_bounds__(256) void mlp_k(
    const bf16* __restrict__ X, const bf16* __restrict__ W1T,   // [768][192]
    const bf16* __restrict__ W2T,                               // [192][768]
    const float* __restrict__ b1, const float* __restrict__ b2,
    float* __restrict__ yio)
{
    constexpr int K = 192;
    __shared__ bf16 As[3][128 * 64];     // X tile: 48 KiB
    __shared__ char Hs[32768];           // hid slice [128 m][128 n1] bf16, swizzled
    const int tid = threadIdx.x;
    const int w = tid >> 6, lane = tid & 63;
    const int w0 = w & 1, w1 = w >> 1;
    const int r16 = lane & 15, g8 = (lane >> 4) * 8, q4 = (lane >> 4) * 4;

    u32 bid = blockIdx.x;
    bid = (bid & 7) * 98 + (bid >> 3);   // 784 % 8 == 0, bijective
    const int tm0 = (int)bid * 128;

    // --- stage X tile (one shot, as gemm_ss) ---
    const bf16* gA[4];
    #pragma unroll
    for (int j = 0; j < 4; ++j) {
        int c = (w * 4 + j) * 64 + lane;
        int l = c ^ ((c >> 3) & 7);
        gA[j] = X + (size_t)(tm0 + (c >> 3)) * K + (l & 7) * 8;
    }
    #pragma unroll
    for (int t = 0; t < 3; ++t)
        #pragma unroll
        for (int j = 0; j < 4; ++j)
            gload_lds16(gA[j] + (t << 6), (char*)&As[t][0] + (size_t)(w * 4 + j) * 1024);
    __syncthreads();

    f32x4 acc2[4][6] = {};               // persistent y accumulator (64m x 96n2 per wave)

    #pragma unroll 1
    for (int s = 0; s < 6; ++s) {
        // ---- phase A: acc1 = X(64m) @ W1 slice (64 n1 for this wave) ----
        f32x4 acc1[4][4] = {};
        const bf16* w1b = W1T + (size_t)(s * 128 + w0 * 64 + r16) * K + g8;
        #pragma unroll
        for (int t = 0; t < 3; ++t) {
            const char* ab = (const char*)&As[t][0];
            #pragma unroll
            for (int k32 = 0; k32 < 2; ++k32) {
                int kg = t * 64 + k32 * 32;
                int kcolb = k32 * 64 + g8 * 2;
                bf16x8 wf[4], xf[4];
                #pragma unroll
                for (int n = 0; n < 4; ++n)
                    wf[n] = *(const bf16x8*)(w1b + (size_t)(n * 16) * K + kg);
                #pragma unroll
                for (int m = 0; m < 4; ++m) {
                    int row = w1 * 64 + m * 16 + r16;
                    int byte = row * 128 + kcolb;
                    xf[m] = *(const bf16x8*)(ab + (byte ^ ((row & 7) << 4)));
                }
                #pragma unroll
                for (int m = 0; m < 4; ++m)
                    #pragma unroll
                    for (int n = 0; n < 4; ++n)
                        acc1[m][n] = __builtin_amdgcn_mfma_f32_16x16x32_bf16(wf[n], xf[m], acc1[m][n], 0, 0, 0);
            }
        }
        // ---- bias + gelu + pack to Hs (lane: m fixed, 4 consecutive n1) ----
        #pragma unroll
        for (int m = 0; m < 4; ++m) {
            int mloc = w1 * 64 + m * 16 + r16;
            #pragma unroll
            for (int n = 0; n < 4; ++n) {
                int n1loc = w0 * 64 + n * 16 + q4;
                f32x4 bv = *(const f32x4*)(b1 + s * 128 + n1loc);
                u32 p0, p1;
                {
                    float v0 = gelu_f(acc1[m][n][0] + bv[0]);
                    float v1 = gelu_f(acc1[m][n][1] + bv[1]);
                    float v2 = gelu_f(acc1[m][n][2] + bv[2]);
                    float v3 = gelu_f(acc1[m][n][3] + bv[3]);
                    p0 = (u32)f2b(v0) | ((u32)f2b(v1) << 16);
                    p1 = (u32)f2b(v2) | ((u32)f2b(v3) << 16);
                }
                int byte = (mloc * 256 + n1loc * 2) ^ ((mloc & 7) << 4);
                *(u32*)(&Hs[0] + byte) = p0;
                *(u32*)(&Hs[0] + byte + 4) = p1;
            }
        }
        __syncthreads();   // Hs complete

        // ---- phase B: acc2 += Hs(64m x 128) @ W2 slice (96 n2 for this wave) ----
        const bf16* w2b = W2T + (size_t)(w0 * 96 + r16) * HIDN + s * 128 + g8;
        #pragma unroll
        for (int k32 = 0; k32 < 4; ++k32) {
            int kcolb = k32 * 64 + g8 * 2;
            bf16x8 wf[6], hf[4];
            #pragma unroll
            for (int n = 0; n < 6; ++n)
                wf[n] = *(const bf16x8*)(w2b + (size_t)(n * 16) * HIDN + k32 * 32);
            #pragma unroll
            for (int m = 0; m < 4; ++m) {
                int row = w1 * 64 + m * 16 + r16;
                int byte = row * 256 + kcolb;
                hf[m] = *(const bf16x8*)(&Hs[0] + (byte ^ ((row & 7) << 4)));
            }
            #pragma unroll
            for (int m = 0; m < 4; ++m)
                #pragma unroll
                for (int n = 0; n < 6; ++n)
                    acc2[m][n] = __builtin_amdgcn_mfma_f32_16x16x32_bf16(wf[n], hf[m], acc2[m][n], 0, 0, 0);
        }
        __syncthreads();   // before next slice overwrites Hs
    }

    // ---- epilogue: y = acc2 + b2 + y (in place, fp32) ----
    #pragma unroll
    for (int m = 0; m < 4; ++m) {
        int mm = tm0 + w1 * 64 + m * 16 + r16;
        size_t rowbase = (size_t)mm * CC;
        #pragma unroll
        for (int n = 0; n < 6; ++n) {
            int col = w0 * 96 + n * 16 + q4;
            f32x4 bv = *(const f32x4*)(b2 + col);
            f32x4 yv = *(const f32x4*)(yio + rowbase + col);
            f32x4 v;
            #pragma unroll
            for (int r = 0; r < 4; ++r) v[r] = acc2[m][n][r] + bv[r] + yv[r];
            *(f32x4*)(yio + rowbase + col) = v;
        }
    }
}

// ---------------- MFMA attention: block = 1 window (384 thr = 6 waves, one per head). ----------------
__global__ __launch_bounds__(384) void attn_m(const bf16* __restrict__ qkv,
                                              const float* __restrict__ bm,
                                              bf16* __restrict__ out)
{
    __shared__ char Pl[6][8192];    // P[q][kk] bf16, byte = q*128+kk*2 ^ ((q&7)<<4)
    __shared__ char Vt[6][4096];    // V^T[d][kk] bf16, byte = d*128+kk*2 ^ ((d&7)<<4)
    const int w = blockIdx.x;
    const int h = threadIdx.x >> 6, l = threadIdx.x & 63;
    const int w49 = w * 49;
    const int wl = w & 63;
    const int cls = (((wl >> 3) == 7) ? 2 : 0) + (((wl & 7) == 7) ? 1 : 0);
    const int hi8 = (l >> 4) * 8, lo = l & 15;

    {
        const bf16* vbase = qkv + ((size_t)(12 + h) * NTOK + w49) * 32;
        #pragma unroll
        for (int it = 0; it < 4; ++it) {
            int c = it * 64 + l;
            int kk = c >> 2, off = (c & 3) * 8;
            bf16x8 v = {};
            if (c < 196) v = *(const bf16x8*)(vbase + kk * 32 + off);
            #pragma unroll
            for (int j = 0; j < 8; ++j) {
                int d = off + j;
                int byte = (d * 128 + kk * 2) ^ ((d & 7) << 4);
                *(bf16*)(&Vt[h][0] + byte) = ((const bf16*)&v)[j];
            }
        }
    }

    const bf16* qb = qkv + ((size_t)h * NTOK + w49) * 32 + hi8;
    const bf16* kb = qkv + ((size_t)(6 + h) * NTOK + w49) * 32 + hi8;
    bf16x8 af[4], bf_[4];
    #pragma unroll
    for (int mt = 0; mt < 4; ++mt) af[mt] = *(const bf16x8*)(kb + (size_t)(mt * 16 + lo) * 32);
    #pragma unroll
    for (int ntt = 0; ntt < 4; ++ntt) bf_[ntt] = *(const bf16x8*)(qb + (size_t)(ntt * 16 + lo) * 32);
    f32x4 acc[4][4] = {};
    #pragma unroll
    for (int mt = 0; mt < 4; ++mt)
        #pragma unroll
        for (int ntt = 0; ntt < 4; ++ntt)
            acc[mt][ntt] = __builtin_amdgcn_mfma_f32_16x16x32_bf16(af[mt], bf_[ntt], acc[mt][ntt], 0, 0, 0);

    const float scale = 0.17677669529663689f;   // 32^-0.5
    const float* bmb = bm + ((size_t)(cls * 6 + h) << 4) * 256;
    #pragma unroll
    for (int mt = 0; mt < 4; ++mt)
        #pragma unroll
        for (int ntt = 0; ntt < 4; ++ntt) {
            f32x4 bmv = *(const f32x4*)(bmb + (mt * 4 + ntt) * 256 + l * 4);
            #pragma unroll
            for (int r = 0; r < 4; ++r) acc[mt][ntt][r] = acc[mt][ntt][r] * scale + bmv[r];
        }

    float inv[4], mx[4];
    #pragma unroll
    for (int ntt = 0; ntt < 4; ++ntt) {
        float m_ = -1e30f;
        #pragma unroll
        for (int mt = 0; mt < 4; ++mt)
            #pragma unroll
            for (int r = 0; r < 4; ++r) m_ = fmaxf(m_, acc[mt][ntt][r]);
        m_ = fmaxf(m_, __shfl_xor(m_, 16));
        m_ = fmaxf(m_, __shfl_xor(m_, 32));
        mx[ntt] = m_;
    }
    #pragma unroll
    for (int ntt = 0; ntt < 4; ++ntt) {
        float s_ = 0.f;
        #pragma unroll
        for (int mt = 0; mt < 4; ++mt)
            #pragma unroll
            for (int r = 0; r < 4; ++r) {
                float e = __expf(acc[mt][ntt][r] - mx[ntt]);
                acc[mt][ntt][r] = e;
                s_ += e;
            }
        s_ += __shfl_xor(s_, 16);
        s_ += __shfl_xor(s_, 32);
        inv[ntt] = 1.0f / s_;
    }

    #pragma unroll
    for (int mt = 0; mt < 4; ++mt)
        #pragma unroll
        for (int ntt = 0; ntt < 4; ++ntt)
            #pragma unroll
            for (int rp = 0; rp < 4; rp += 2) {
                u32 pk = (u32)f2b(acc[mt][ntt][rp]) | ((u32)f2b(acc[mt][ntt][rp + 1]) << 16);
                int kk = mt * 16 + (l >> 4) * 4 + rp;
                int q  = ntt * 16 + lo;
                int byte = (q * 128 + kk * 2) ^ ((q & 7) << 4);
                *(u32*)(&Pl[h][0] + byte) = pk;
            }

    f32x4 o[4][2] = {};
    #pragma unroll
    for (int ks = 0; ks < 2; ++ks) {
        int kb_ = (ks * 32 + hi8) * 2;
        bf16x8 pa[4], vb[2];
        #pragma unroll
        for (int qt = 0; qt < 4; ++qt) {
            int row = qt * 16 + lo;
            pa[qt] = *(const bf16x8*)(&Pl[h][0] + ((row * 128 + kb_) ^ ((row & 7) << 4)));
        }
        #pragma unroll
        for (int dt = 0; dt < 2; ++dt) {
            int row = dt * 16 + lo;
            vb[dt] = *(const bf16x8*)(&Vt[h][0] + ((row * 128 + kb_) ^ ((row & 7) << 4)));
        }
        #pragma unroll
        for (int qt = 0; qt < 4; ++qt)
            #pragma unroll
            for (int dt = 0; dt < 2; ++dt)
                o[qt][dt] = __builtin_amdgcn_mfma_f32_16x16x32_bf16(pa[qt], vb[dt], o[qt][dt], 0, 0, 0);
    }

    #pragma unroll
    for (int qt = 0; qt < 4; ++qt)
        #pragma unroll
        for (int r = 0; r < 4; ++r) {
            int qrow = (l >> 4) * 4 + r;
            float iv = __shfl(inv[qt], qrow);
            int q = qt * 16 + qrow;
            if (q < 49) {
                size_t ob = (size_t)(w49 + q) * CC + h * 32 + lo;
                out[ob]      = __float2bfloat16(o[qt][0][r] * iv);
                out[ob + 16] = __float2bfloat16(o[qt][1][r] * iv);
            }
        }
}

// ---------------- launch ----------------
extern "C" void kernel_launch(void* const* d_in, const int* in_sizes, int n_in,
                              void* d_out, int out_size, void* d_ws, size_t ws_size,
                              hipStream_t stream) {
    const float* x      = (const float*)d_in[0];
    const float* n1g    = (const float*)d_in[1];
    const float* n1b    = (const float*)d_in[2];
    const float* qkv_w  = (const float*)d_in[3];
    const float* qkv_b  = (const float*)d_in[4];
    const float* proj_w = (const float*)d_in[5];
    const float* proj_b = (const float*)d_in[6];
    const float* btab   = (const float*)d_in[7];
    const float* n2g    = (const float*)d_in[8];
    const float* n2b    = (const float*)d_in[9];
    const float* fc1_w  = (const float*)d_in[10];
    const float* fc1_b  = (const float*)d_in[11];
    const float* fc2_w  = (const float*)d_in[12];
    const float* fc2_b  = (const float*)d_in[13];

    char* ws = (char*)d_ws;
    //  xw   [0, 38535168)            bf16 [100352][192]  (LN1 out; reused as LN2 out m)
    //  qkv  [38535168, 154140672)    bf16 head-planar [3][6][NTOK][32]
    //  att  [154140672, 192675840)   bf16 [100352][192]
    //  wt   [192675840, 193560576)   transposed bf16 weights
    //  bm   [193560576, 193953792)   biasmask f32 [4][6][16][256]
    //  y (fp32) lives in d_out.  (hid buffer no longer needed: MLP fused)
    const size_t XW_OFF  = 0;
    const size_t QKV_OFF = 38535168;
    const size_t ATT_OFF = 154140672;
    const size_t WT_OFF  = 192675840;
    const size_t BM_OFF  = 193560576;
    if (ws_size < 193953792ull) return;   // diagnostic: zeros signature (absmax ~5.59)

    bf16* xw   = (bf16*)(ws + XW_OFF);
    bf16* mbuf = (bf16*)(ws + XW_OFF);
    bf16* qkvb = (bf16*)(ws + QKV_OFF);
    bf16* attb = (bf16*)(ws + ATT_OFF);
    float* yf  = (float*)d_out;
    bf16* wt   = (bf16*)(ws + WT_OFF);
    float* bmt = (float*)(ws + BM_OFF);
    bf16* qkv_wT  = wt;                       // [576][192]
    bf16* proj_wT = wt + 110592;              // [192][192]
    bf16* fc1_wT  = wt + 147456;              // [768][192]
    bf16* fc2_wT  = wt + 294912;              // [192][768]

    transpose_k<<<dim3(432), 256, 0, stream>>>(qkv_w, qkv_wT, 192, 576);
    transpose_k<<<dim3(144), 256, 0, stream>>>(proj_w, proj_wT, 192, 192);
    transpose_k<<<dim3(576), 256, 0, stream>>>(fc1_w, fc1_wT, 192, 768);
    transpose_k<<<dim3(576), 256, 0, stream>>>(fc2_w, fc2_wT, 768, 192);
    bm_k<<<dim3(384), 256, 0, stream>>>(btab, bmt);

    ln_k<true><<<NTOK / 4, 256, 0, stream>>>(x, n1g, n1b, xw);

    gemm_ss<4, 9><<<dim3(9, 784), 256, 0, stream>>>(
        xw, qkv_wT, qkv_b, 576, qkvb, nullptr, nullptr, nullptr);
    attn_m<<<dim3(2048), 384, 0, stream>>>(qkvb, bmt, attb);
    gemm_ss<1, 3><<<dim3(3, 784), 256, 0, stream>>>(
        attb, proj_wT, proj_b, 192, nullptr, yf, x, nullptr);

    ln_k<false><<<NTOK / 4, 256, 0, stream>>>(yf, n2g, n2b, mbuf);

    mlp_k<<<dim3(784), 256, 0, stream>>>(
        mbuf, fc1_wT, fc2_wT, fc1_b, fc2_b, yf);
}

// Round 15
// 391.402 us; speedup vs baseline: 1.2726x; 1.2726x over previous
//
#include <hip/hip_runtime.h>
#include <hip/hip_bf16.h>

typedef __hip_bfloat16 bf16;
typedef float f32x4 __attribute__((ext_vector_type(4)));
typedef short bf16x8 __attribute__((ext_vector_type(8)));
typedef short short4v __attribute__((ext_vector_type(4)));
typedef unsigned int u32;

#define NTOK 100352   // 32*56*56 tokens = 2048 windows * 49
#define CC 192
#define HIDN 768

__device__ __forceinline__ float b2f(unsigned short u) {
    union { unsigned int u32v; float f; } x; x.u32v = ((unsigned int)u) << 16; return x.f;
}
__device__ __forceinline__ unsigned short f2b(float f) {
    union { float f; unsigned int u; } x; x.f = f;
    unsigned int r = x.u + 0x7FFF + ((x.u >> 16) & 1);
    return (unsigned short)(r >> 16);
}
// sigmoid-form gelu (validated R13/R14: absmax unchanged at 0.03125)
__device__ __forceinline__ float gelu_f(float x) {
    return x / (1.0f + __expf(-1.702f * x));
}

typedef __attribute__((address_space(1))) const unsigned char gas_u8;
typedef __attribute__((address_space(3))) unsigned char las_u8;
__device__ __forceinline__ void gload_lds16(const void* g, void* l) {
    __builtin_amdgcn_global_load_lds((gas_u8*)g, (las_u8*)l, 16, 0, 0);
}

// ---------------- weight prep: fp32 src [R][C] -> bf16 dst[c*R + r] ----------------
__global__ void transpose_k(const float* __restrict__ src, bf16* __restrict__ dst, int R, int C) {
    int idx = blockIdx.x * 256 + threadIdx.x;
    if (idx >= R * C) return;
    int r = idx / C, c = idx % C;
    dst[(size_t)c * R + r] = __float2bfloat16(src[idx]);
}

// ---------------- biasmask table: [cls][head][mt][nt][lane][reg] f32, acc-frag layout. ----------------
__global__ void bm_k(const float* __restrict__ btab, float* __restrict__ bm) {
    int idx = blockIdx.x * 256 + threadIdx.x;           // 4*6*16*256 = 98304
    if (idx >= 98304) return;
    int reg = idx & 3, lane = (idx >> 2) & 63, tile = (idx >> 8) & 15;
    int rest = idx >> 12, h = rest % 6, cls = rest / 6;
    int mt = tile >> 2, nt = tile & 3;
    int kk = mt * 16 + (lane >> 4) * 4 + reg;
    int q  = nt * 16 + (lane & 15);
    float v;
    if (kk >= 49 || q >= 49) v = -1e9f;
    else {
        int i1 = q / 7, j1 = q % 7, i2 = kk / 7, j2 = kk % 7;
        v = btab[((i1 - i2 + 6) * 13 + (j1 - j2 + 6)) * 6 + h];
        int hb7 = cls >> 1, wb7 = cls & 1;
        int r1 = (hb7 ? (i1 < 4 ? 1 : 2) : 0) * 3 + (wb7 ? (j1 < 4 ? 1 : 2) : 0);
        int r2 = (hb7 ? (i2 < 4 ? 1 : 2) : 0) * 3 + (wb7 ? (j2 < 4 ? 1 : 2) : 0);
        if (r1 != r2) v -= 100.0f;
    }
    bm[idx] = v;
}

// ---------------- LayerNorm (wave per token) -> bf16 rows. ----------------
template<bool GATHER>
__global__ __launch_bounds__(256) void ln_k(const float* __restrict__ src,
                                            const float* __restrict__ gamma,
                                            const float* __restrict__ beta,
                                            bf16* __restrict__ dst) {
    int wave = threadIdx.x >> 6, lane = threadIdx.x & 63;
    int t = blockIdx.x * 4 + wave;           // output token index
    size_t srow;
    if (GATHER) {
        int w = t / 49, n = t % 49;
        int b = w >> 6, wl = w & 63, hb = wl >> 3, wb = wl & 7;
        int i = n / 7, j = n % 7;
        int sh = hb * 7 + i + 3; if (sh >= 56) sh -= 56;   // roll(-3): src=(dst+3)%56
        int sw = wb * 7 + j + 3; if (sw >= 56) sw -= 56;
        srow = ((size_t)(b * 56 + sh) * 56 + sw) * CC;
    } else {
        srow = (size_t)t * CC;
    }
    float v[4];
    int c = lane * 4;
    float sum = 0.f, sq = 0.f;
    if (lane < 48) {
        f32x4 d = *(const f32x4*)(src + srow + c);
        #pragma unroll
        for (int q = 0; q < 4; ++q) { v[q] = d[q]; sum += v[q]; sq += v[q] * v[q]; }
    }
    #pragma unroll
    for (int off = 1; off < 64; off <<= 1) { sum += __shfl_xor(sum, off); sq += __shfl_xor(sq, off); }
    float mu = sum * (1.0f / 192.0f);
    float var = sq * (1.0f / 192.0f) - mu * mu;
    float rstd = rsqrtf(var + 1e-5f);
    if (lane < 48) {
        f32x4 gg = *(const f32x4*)(gamma + c);
        f32x4 bb = *(const f32x4*)(beta + c);
        short4v o;
        #pragma unroll
        for (int q = 0; q < 4; ++q) {
            float val = (v[q] - mu) * rstd * gg[q] + bb[q];
            o[q] = (short)f2b(val);
        }
        *(short4v*)(dst + (size_t)t * CC + c) = o;
    }
}

// ---------------- Tiled MFMA GEMM, K9 structure scaled to BM=256 (512 thr, 8 waves 4Mx2N).
// Per wave 64x32 (acc[4][2]); dbuf LDS (A 2x32KB + B 2x8KB = 80KB -> 2 blocks/CU, 16 waves/CU);
// global_load_lds w16 staging, validated XOR swizzle (linear dest + inv-swizzled src + swz read);
// XCD-chunked bijective block swizzle. D frag: col=lane&15, row=(lane>>4)*4+reg (validated).
// EPI 0: +bias -> bf16 outb; EPI 1: +bias, reverse+roll(+3,+3) scatter, outf=xres+val;
// EPI 2: +bias, gelu -> bf16; EPI 3: +bias+yin -> fp32 outf; EPI 4: head-planar bf16.
template<int EPI>
__global__ __launch_bounds__(512) void gemm_t(
    const bf16* __restrict__ X, const bf16* __restrict__ WT,
    const float* __restrict__ bias, int K, int N,
    bf16* __restrict__ outb, float* __restrict__ outf,
    const float* __restrict__ xres, const float* __restrict__ yin)
{
    __shared__ bf16 As[2][256 * 64];   // 32 KiB each
    __shared__ bf16 Bs[2][64 * 64];    // 8 KiB each
    const int tid = threadIdx.x;
    const int w = tid >> 6, lane = tid & 63;
    const int w0 = w & 1, w1 = w >> 1;            // w1 in 0..3: M quadrant

    const u32 nwg = gridDim.x * gridDim.y;
    u32 bid = blockIdx.y * gridDim.x + blockIdx.x;
    bid = (bid & 7) * (nwg >> 3) + (bid >> 3);    // bijective (all grids % 8 == 0)
    const int tn0 = (bid % gridDim.x) * 64;
    const int tm0 = (bid / gridDim.x) * 256;

    const int r16 = lane & 15, g8 = (lane >> 4) * 8;

    // staging addresses hoisted; A: 2048 16B-chunks (4/thread), B: 512 (1/thread)
    const bf16* gA[4];
    const bf16* gB;
    #pragma unroll
    for (int j = 0; j < 4; ++j) {
        int c = (w * 4 + j) * 64 + lane;
        int l = c ^ ((c >> 3) & 7);               // inverse swizzle on source
        gA[j] = X + (size_t)(tm0 + (c >> 3)) * K + (l & 7) * 8;
    }
    {
        int c = w * 64 + lane;
        int l = c ^ ((c >> 3) & 7);
        gB = WT + (size_t)(tn0 + (c >> 3)) * K + (l & 7) * 8;
    }

    auto stage = [&](int buf, int kk) {
        #pragma unroll
        for (int j = 0; j < 4; ++j)
            gload_lds16(gA[j] + kk, (char*)&As[buf][0] + (size_t)(w * 4 + j) * 1024);
        gload_lds16(gB + kk, (char*)&Bs[buf][0] + (size_t)w * 1024);
    };

    f32x4 acc[4][2] = {};
    const int nt = K >> 6;
    stage(0, 0);
    __syncthreads();
    for (int t = 0; t < nt; ++t) {
        int buf = t & 1;
        if (t + 1 < nt) stage(buf ^ 1, (t + 1) << 6);
        const char* ab = (const char*)&As[buf][0];
        const char* bb_ = (const char*)&Bs[buf][0];
        #pragma unroll
        for (int k32 = 0; k32 < 2; ++k32) {
            int kcolb = k32 * 64 + g8 * 2;
            bf16x8 a[4], b[2];
            #pragma unroll
            for (int m = 0; m < 4; ++m) {
                int row = w1 * 64 + m * 16 + r16;
                int byte = row * 128 + kcolb;
                a[m] = *(const bf16x8*)(ab + (byte ^ ((row & 7) << 4)));
            }
            #pragma unroll
            for (int n = 0; n < 2; ++n) {
                int row = w0 * 32 + n * 16 + r16;
                int byte = row * 128 + kcolb;
                b[n] = *(const bf16x8*)(bb_ + (byte ^ ((row & 7) << 4)));
            }
            #pragma unroll
            for (int m = 0; m < 4; ++m)
                #pragma unroll
                for (int n = 0; n < 2; ++n)
                    acc[m][n] = __builtin_amdgcn_mfma_f32_16x16x32_bf16(a[m], b[n], acc[m][n], 0, 0, 0);
        }
        __syncthreads();
    }

    // K9-validated epilogue (col = lane&15 on N; row = (lane>>4)*4+reg on M)
    #pragma unroll
    for (int n = 0; n < 2; ++n) {
        int col = tn0 + w0 * 32 + n * 16 + r16;
        float bv = bias[col];
        #pragma unroll
        for (int m = 0; m < 4; ++m) {
            #pragma unroll
            for (int r = 0; r < 4; ++r) {
                int mm = tm0 + w1 * 64 + m * 16 + (lane >> 4) * 4 + r;
                float val = acc[m][n][r] + bv;
                if (EPI == 0) {
                    outb[(size_t)mm * N + col] = __float2bfloat16(val);
                } else if (EPI == 1) {
                    int ww = mm / 49, nn = mm % 49;
                    int b_ = ww >> 6, wl = ww & 63, hb = wl >> 3, wb = wl & 7;
                    int i = nn / 7, j = nn % 7;
                    int oh = hb * 7 + i + 3; if (oh >= 56) oh -= 56;   // roll(+3)
                    int ow = wb * 7 + j + 3; if (ow >= 56) ow -= 56;
                    size_t dst = ((size_t)(b_ * 56 + oh) * 56 + ow) * CC + col;
                    outf[dst] = xres[dst] + val;
                } else if (EPI == 2) {
                    outb[(size_t)mm * N + col] = __float2bfloat16(gelu_f(val));
                } else if (EPI == 3) {
                    outf[(size_t)mm * N + col] = val + yin[(size_t)mm * N + col];
                } else {
                    outb[((size_t)(col >> 5) * NTOK + mm) * 32 + (col & 31)] = __float2bfloat16(val);
                }
            }
        }
    }
}

// ---------------- MFMA attention: block = 1 window (384 thr = 6 waves, one per head). ----------------
__global__ __launch_bounds__(384) void attn_m(const bf16* __restrict__ qkv,
                                              const float* __restrict__ bm,
                                              bf16* __restrict__ out)
{
    __shared__ char Pl[6][8192];    // P[q][kk] bf16, byte = q*128+kk*2 ^ ((q&7)<<4)
    __shared__ char Vt[6][4096];    // V^T[d][kk] bf16, byte = d*128+kk*2 ^ ((d&7)<<4)
    const int w = blockIdx.x;
    const int h = threadIdx.x >> 6, l = threadIdx.x & 63;
    const int w49 = w * 49;
    const int wl = w & 63;
    const int cls = (((wl >> 3) == 7) ? 2 : 0) + (((wl & 7) == 7) ? 1 : 0);
    const int hi8 = (l >> 4) * 8, lo = l & 15;

    {
        const bf16* vbase = qkv + ((size_t)(12 + h) * NTOK + w49) * 32;
        #pragma unroll
        for (int it = 0; it < 4; ++it) {
            int c = it * 64 + l;
            int kk = c >> 2, off = (c & 3) * 8;
            bf16x8 v = {};
            if (c < 196) v = *(const bf16x8*)(vbase + kk * 32 + off);
            #pragma unroll
            for (int j = 0; j < 8; ++j) {
                int d = off + j;
                int byte = (d * 128 + kk * 2) ^ ((d & 7) << 4);
                *(bf16*)(&Vt[h][0] + byte) = ((const bf16*)&v)[j];
            }
        }
    }

    const bf16* qb = qkv + ((size_t)h * NTOK + w49) * 32 + hi8;
    const bf16* kb = qkv + ((size_t)(6 + h) * NTOK + w49) * 32 + hi8;
    bf16x8 af[4], bf_[4];
    #pragma unroll
    for (int mt = 0; mt < 4; ++mt) af[mt] = *(const bf16x8*)(kb + (size_t)(mt * 16 + lo) * 32);
    #pragma unroll
    for (int ntt = 0; ntt < 4; ++ntt) bf_[ntt] = *(const bf16x8*)(qb + (size_t)(ntt * 16 + lo) * 32);
    f32x4 acc[4][4] = {};
    #pragma unroll
    for (int mt = 0; mt < 4; ++mt)
        #pragma unroll
        for (int ntt = 0; ntt < 4; ++ntt)
            acc[mt][ntt] = __builtin_amdgcn_mfma_f32_16x16x32_bf16(af[mt], bf_[ntt], acc[mt][ntt], 0, 0, 0);

    const float scale = 0.17677669529663689f;   // 32^-0.5
    const float* bmb = bm + ((size_t)(cls * 6 + h) << 4) * 256;
    #pragma unroll
    for (int mt = 0; mt < 4; ++mt)
        #pragma unroll
        for (int ntt = 0; ntt < 4; ++ntt) {
            f32x4 bmv = *(const f32x4*)(bmb + (mt * 4 + ntt) * 256 + l * 4);
            #pragma unroll
            for (int r = 0; r < 4; ++r) acc[mt][ntt][r] = acc[mt][ntt][r] * scale + bmv[r];
        }

    float inv[4], mx[4];
    #pragma unroll
    for (int ntt = 0; ntt < 4; ++ntt) {
        float m_ = -1e30f;
        #pragma unroll
        for (int mt = 0; mt < 4; ++mt)
            #pragma unroll
            for (int r = 0; r < 4; ++r) m_ = fmaxf(m_, acc[mt][ntt][r]);
        m_ = fmaxf(m_, __shfl_xor(m_, 16));
        m_ = fmaxf(m_, __shfl_xor(m_, 32));
        mx[ntt] = m_;
    }
    #pragma unroll
    for (int ntt = 0; ntt < 4; ++ntt) {
        float s_ = 0.f;
        #pragma unroll
        for (int mt = 0; mt < 4; ++mt)
            #pragma unroll
            for (int r = 0; r < 4; ++r) {
                float e = __expf(acc[mt][ntt][r] - mx[ntt]);
                acc[mt][ntt][r] = e;
                s_ += e;
            }
        s_ += __shfl_xor(s_, 16);
        s_ += __shfl_xor(s_, 32);
        inv[ntt] = 1.0f / s_;
    }

    #pragma unroll
    for (int mt = 0; mt < 4; ++mt)
        #pragma unroll
        for (int ntt = 0; ntt < 4; ++ntt)
            #pragma unroll
            for (int rp = 0; rp < 4; rp += 2) {
                u32 pk = (u32)f2b(acc[mt][ntt][rp]) | ((u32)f2b(acc[mt][ntt][rp + 1]) << 16);
                int kk = mt * 16 + (l >> 4) * 4 + rp;
                int q  = ntt * 16 + lo;
                int byte = (q * 128 + kk * 2) ^ ((q & 7) << 4);
                *(u32*)(&Pl[h][0] + byte) = pk;
            }

    f32x4 o[4][2] = {};
    #pragma unroll
    for (int ks = 0; ks < 2; ++ks) {
        int kb_ = (ks * 32 + hi8) * 2;
        bf16x8 pa[4], vb[2];
        #pragma unroll
        for (int qt = 0; qt < 4; ++qt) {
            int row = qt * 16 + lo;
            pa[qt] = *(const bf16x8*)(&Pl[h][0] + ((row * 128 + kb_) ^ ((row & 7) << 4)));
        }
        #pragma unroll
        for (int dt = 0; dt < 2; ++dt) {
            int row = dt * 16 + lo;
            vb[dt] = *(const bf16x8*)(&Vt[h][0] + ((row * 128 + kb_) ^ ((row & 7) << 4)));
        }
        #pragma unroll
        for (int qt = 0; qt < 4; ++qt)
            #pragma unroll
            for (int dt = 0; dt < 2; ++dt)
                o[qt][dt] = __builtin_amdgcn_mfma_f32_16x16x32_bf16(pa[qt], vb[dt], o[qt][dt], 0, 0, 0);
    }

    #pragma unroll
    for (int qt = 0; qt < 4; ++qt)
        #pragma unroll
        for (int r = 0; r < 4; ++r) {
            int qrow = (l >> 4) * 4 + r;
            float iv = __shfl(inv[qt], qrow);
            int q = qt * 16 + qrow;
            if (q < 49) {
                size_t ob = (size_t)(w49 + q) * CC + h * 32 + lo;
                out[ob]      = __float2bfloat16(o[qt][0][r] * iv);
                out[ob + 16] = __float2bfloat16(o[qt][1][r] * iv);
            }
        }
}

// ---------------- launch ----------------
extern "C" void kernel_launch(void* const* d_in, const int* in_sizes, int n_in,
                              void* d_out, int out_size, void* d_ws, size_t ws_size,
                              hipStream_t stream) {
    const float* x      = (const float*)d_in[0];
    const float* n1g    = (const float*)d_in[1];
    const float* n1b    = (const float*)d_in[2];
    const float* qkv_w  = (const float*)d_in[3];
    const float* qkv_b  = (const float*)d_in[4];
    const float* proj_w = (const float*)d_in[5];
    const float* proj_b = (const float*)d_in[6];
    const float* btab   = (const float*)d_in[7];
    const float* n2g    = (const float*)d_in[8];
    const float* n2b    = (const float*)d_in[9];
    const float* fc1_w  = (const float*)d_in[10];
    const float* fc1_b  = (const float*)d_in[11];
    const float* fc2_w  = (const float*)d_in[12];
    const float* fc2_b  = (const float*)d_in[13];

    char* ws = (char*)d_ws;
    //  xw   [0, 38535168)            bf16 [100352][192]  (LN1 out; reused as LN2 out m)
    //  qkv  [38535168, 154140672)    bf16 head-planar [3][6][NTOK][32]
    //        (MLP phase: hid bf16 [100352][768] reuses [38535168, 192675840))
    //  att  [154140672, 192675840)   bf16 [100352][192]
    //  wt   [192675840, 193560576)   transposed bf16 weights
    //  bm   [193560576, 193953792)   biasmask f32 [4][6][16][256]
    //  y (fp32) lives in d_out.
    const size_t XW_OFF  = 0;
    const size_t QKV_OFF = 38535168;
    const size_t ATT_OFF = 154140672;
    const size_t WT_OFF  = 192675840;
    const size_t BM_OFF  = 193560576;
    if (ws_size < 193953792ull) return;   // diagnostic: zeros signature (absmax ~5.59)

    bf16* xw   = (bf16*)(ws + XW_OFF);
    bf16* mbuf = (bf16*)(ws + XW_OFF);
    bf16* qkvb = (bf16*)(ws + QKV_OFF);
    bf16* attb = (bf16*)(ws + ATT_OFF);
    bf16* hidb = (bf16*)(ws + QKV_OFF);      // MLP phase reuse
    float* yf  = (float*)d_out;
    bf16* wt   = (bf16*)(ws + WT_OFF);
    float* bmt = (float*)(ws + BM_OFF);
    bf16* qkv_wT  = wt;                       // [576][192]
    bf16* proj_wT = wt + 110592;              // [192][192]
    bf16* fc1_wT  = wt + 147456;              // [768][192]
    bf16* fc2_wT  = wt + 294912;              // [192][768]

    transpose_k<<<dim3(432), 256, 0, stream>>>(qkv_w, qkv_wT, 192, 576);
    transpose_k<<<dim3(144), 256, 0, stream>>>(proj_w, proj_wT, 192, 192);
    transpose_k<<<dim3(576), 256, 0, stream>>>(fc1_w, fc1_wT, 192, 768);
    transpose_k<<<dim3(576), 256, 0, stream>>>(fc2_w, fc2_wT, 768, 192);
    bm_k<<<dim3(384), 256, 0, stream>>>(btab, bmt);

    ln_k<true><<<NTOK / 4, 256, 0, stream>>>(x, n1g, n1b, xw);

    gemm_t<4><<<dim3(9, 392), 512, 0, stream>>>(
        xw, qkv_wT, qkv_b, 192, 576, qkvb, nullptr, nullptr, nullptr);
    attn_m<<<dim3(2048), 384, 0, stream>>>(qkvb, bmt, attb);
    gemm_t<1><<<dim3(3, 392), 512, 0, stream>>>(
        attb, proj_wT, proj_b, 192, 192, nullptr, yf, x, nullptr);

    ln_k<false><<<NTOK / 4, 256, 0, stream>>>(yf, n2g, n2b, mbuf);

    gemm_t<2><<<dim3(12, 392), 512, 0, stream>>>(
        mbuf, fc1_wT, fc1_b, 192, 768, hidb, nullptr, nullptr, nullptr);
    gemm_t<3><<<dim3(3, 392), 512, 0, stream>>>(
        hidb, fc2_wT, fc2_b, 768, 192, nullptr, yf, nullptr, yf);
}

// Round 17
// 343.626 us; speedup vs baseline: 1.4495x; 1.1390x over previous
//
#include <hip/hip_runtime.h>
#include <hip/hip_bf16.h>

typedef __hip_bfloat16 bf16;
typedef float f32x4 __attribute__((ext_vector_type(4)));
typedef short bf16x8 __attribute__((ext_vector_type(8)));
typedef short short4v __attribute__((ext_vector_type(4)));
typedef unsigned int u32;

#define NTOK 100352   // 32*56*56 tokens = 2048 windows * 49
#define CC 192
#define HIDN 768

__device__ __forceinline__ float b2f(unsigned short u) {
    union { unsigned int u32v; float f; } x; x.u32v = ((unsigned int)u) << 16; return x.f;
}
__device__ __forceinline__ unsigned short f2b(float f) {
    union { float f; unsigned int u; } x; x.f = f;
    unsigned int r = x.u + 0x7FFF + ((x.u >> 16) & 1);
    return (unsigned short)(r >> 16);
}
// sigmoid-form gelu (validated R13-R15: absmax unchanged at 0.03125)
__device__ __forceinline__ float gelu_f(float x) {
    return x / (1.0f + __expf(-1.702f * x));
}

typedef __attribute__((address_space(1))) const unsigned char gas_u8;
typedef __attribute__((address_space(3))) unsigned char las_u8;
__device__ __forceinline__ void gload_lds16(const void* g, void* l) {
    __builtin_amdgcn_global_load_lds((gas_u8*)g, (las_u8*)l, 16, 0, 0);
}

// ---------------- merged prep: 4 weight transposes (fp32->bf16) + biasmask table ----------------
__global__ void prep_k(const float* __restrict__ qkv_w, const float* __restrict__ proj_w,
                       const float* __restrict__ fc1_w, const float* __restrict__ fc2_w,
                       const float* __restrict__ btab,
                       bf16* __restrict__ qkvT, bf16* __restrict__ projT,
                       bf16* __restrict__ fc1T, bf16* __restrict__ fc2T,
                       float* __restrict__ bm)
{
    int idx = blockIdx.x * 256 + threadIdx.x;
    if (idx < 110592) {                       // qkvT [576][192]
        int c = idx / 192, r = idx % 192;
        qkvT[idx] = __float2bfloat16(qkv_w[(size_t)r * 576 + c]);
    } else if (idx < 147456) {                // projT [192][192]
        int t = idx - 110592, c = t / 192, r = t % 192;
        projT[t] = __float2bfloat16(proj_w[(size_t)r * 192 + c]);
    } else if (idx < 294912) {                // fc1T [768][192]
        int t = idx - 147456, c = t / 192, r = t % 192;
        fc1T[t] = __float2bfloat16(fc1_w[(size_t)r * 768 + c]);
    } else if (idx < 442368) {                // fc2T [192][768]
        int t = idx - 294912, c = t / 768, r = t % 768;
        fc2T[t] = __float2bfloat16(fc2_w[(size_t)r * 192 + c]);
    } else if (idx < 540672) {                // biasmask [4][6][16][256]
        int t = idx - 442368;
        int reg = t & 3, lane = (t >> 2) & 63, tile = (t >> 8) & 15;
        int rest = t >> 12, h = rest % 6, cls = rest / 6;
        int mt = tile >> 2, nt = tile & 3;
        int kk = mt * 16 + (lane >> 4) * 4 + reg;
        int q  = nt * 16 + (lane & 15);
        float v;
        if (kk >= 49 || q >= 49) v = -1e9f;
        else {
            int i1 = q / 7, j1 = q % 7, i2 = kk / 7, j2 = kk % 7;
            v = btab[((i1 - i2 + 6) * 13 + (j1 - j2 + 6)) * 6 + h];
            int hb7 = cls >> 1, wb7 = cls & 1;
            int r1 = (hb7 ? (i1 < 4 ? 1 : 2) : 0) * 3 + (wb7 ? (j1 < 4 ? 1 : 2) : 0);
            int r2 = (hb7 ? (i2 < 4 ? 1 : 2) : 0) * 3 + (wb7 ? (j2 < 4 ? 1 : 2) : 0);
            if (r1 != r2) v -= 100.0f;
        }
        bm[t] = v;
    }
}

// ---------------- LayerNorm (wave per token) -> bf16 rows. ST=float(+GATHER) or bf16. ----------------
template<typename ST, bool GATHER>
__global__ __launch_bounds__(256) void ln_k(const ST* __restrict__ src,
                                            const float* __restrict__ gamma,
                                            const float* __restrict__ beta,
                                            bf16* __restrict__ dst) {
    int wave = threadIdx.x >> 6, lane = threadIdx.x & 63;
    int t = blockIdx.x * 4 + wave;           // output token index
    size_t srow;
    if (GATHER) {
        int w = t / 49, n = t % 49;
        int b = w >> 6, wl = w & 63, hb = wl >> 3, wb = wl & 7;
        int i = n / 7, j = n % 7;
        int sh = hb * 7 + i + 3; if (sh >= 56) sh -= 56;   // roll(-3): src=(dst+3)%56
        int sw = wb * 7 + j + 3; if (sw >= 56) sw -= 56;
        srow = ((size_t)(b * 56 + sh) * 56 + sw) * CC;
    } else {
        srow = (size_t)t * CC;
    }
    float v[4];
    int c = lane * 4;
    float sum = 0.f, sq = 0.f;
    if (lane < 48) {
        if constexpr (sizeof(ST) == 2) {
            short4v d = *(const short4v*)((const bf16*)src + srow + c);
            #pragma unroll
            for (int q = 0; q < 4; ++q) v[q] = b2f((unsigned short)d[q]);
        } else {
            f32x4 d = *(const f32x4*)((const float*)src + srow + c);
            #pragma unroll
            for (int q = 0; q < 4; ++q) v[q] = d[q];
        }
        #pragma unroll
        for (int q = 0; q < 4; ++q) { sum += v[q]; sq += v[q] * v[q]; }
    }
    #pragma unroll
    for (int off = 1; off < 64; off <<= 1) { sum += __shfl_xor(sum, off); sq += __shfl_xor(sq, off); }
    float mu = sum * (1.0f / 192.0f);
    float var = sq * (1.0f / 192.0f) - mu * mu;
    float rstd = rsqrtf(var + 1e-5f);
    if (lane < 48) {
        f32x4 gg = *(const f32x4*)(gamma + c);
        f32x4 bb = *(const f32x4*)(beta + c);
        short4v o;
        #pragma unroll
        for (int q = 0; q < 4; ++q) {
            float val = (v[q] - mu) * rstd * gg[q] + bb[q];
            o[q] = (short)f2b(val);
        }
        *(short4v*)(dst + (size_t)t * CC + c) = o;
    }
}

// ---------------- Tiled MFMA GEMM (R15-validated: BM=256, 512 thr, 8 waves 4Mx2N, dbuf LDS,
// swizzled, XCD-chunked). EPI 2: +bias, gelu -> bf16; EPI 3: +bias + yin(bf16) -> fp32 outf;
// EPI 4: +bias -> head-planar bf16. ----------------
template<int EPI>
__global__ __launch_bounds__(512) void gemm_t(
    const bf16* __restrict__ X, const bf16* __restrict__ WT,
    const float* __restrict__ bias, int K, int N,
    bf16* __restrict__ outb, float* __restrict__ outf,
    const bf16* __restrict__ yin)
{
    __shared__ bf16 As[2][256 * 64];   // 32 KiB each
    __shared__ bf16 Bs[2][64 * 64];    // 8 KiB each
    const int tid = threadIdx.x;
    const int w = tid >> 6, lane = tid & 63;
    const int w0 = w & 1, w1 = w >> 1;

    const u32 nwg = gridDim.x * gridDim.y;
    u32 bid = blockIdx.y * gridDim.x + blockIdx.x;
    bid = (bid & 7) * (nwg >> 3) + (bid >> 3);    // bijective (all grids % 8 == 0)
    const int tn0 = (bid % gridDim.x) * 64;
    const int tm0 = (bid / gridDim.x) * 256;

    const int r16 = lane & 15, g8 = (lane >> 4) * 8;

    const bf16* gA[4];
    const bf16* gB;
    #pragma unroll
    for (int j = 0; j < 4; ++j) {
        int c = (w * 4 + j) * 64 + lane;
        int l = c ^ ((c >> 3) & 7);               // inverse swizzle on source
        gA[j] = X + (size_t)(tm0 + (c >> 3)) * K + (l & 7) * 8;
    }
    {
        int c = w * 64 + lane;
        int l = c ^ ((c >> 3) & 7);
        gB = WT + (size_t)(tn0 + (c >> 3)) * K + (l & 7) * 8;
    }

    auto stage = [&](int buf, int kk) {
        #pragma unroll
        for (int j = 0; j < 4; ++j)
            gload_lds16(gA[j] + kk, (char*)&As[buf][0] + (size_t)(w * 4 + j) * 1024);
        gload_lds16(gB + kk, (char*)&Bs[buf][0] + (size_t)w * 1024);
    };

    f32x4 acc[4][2] = {};
    const int nt = K >> 6;
    stage(0, 0);
    __syncthreads();
    for (int t = 0; t < nt; ++t) {
        int buf = t & 1;
        if (t + 1 < nt) stage(buf ^ 1, (t + 1) << 6);
        const char* ab = (const char*)&As[buf][0];
        const char* bb_ = (const char*)&Bs[buf][0];
        #pragma unroll
        for (int k32 = 0; k32 < 2; ++k32) {
            int kcolb = k32 * 64 + g8 * 2;
            bf16x8 a[4], b[2];
            #pragma unroll
            for (int m = 0; m < 4; ++m) {
                int row = w1 * 64 + m * 16 + r16;
                int byte = row * 128 + kcolb;
                a[m] = *(const bf16x8*)(ab + (byte ^ ((row & 7) << 4)));
            }
            #pragma unroll
            for (int n = 0; n < 2; ++n) {
                int row = w0 * 32 + n * 16 + r16;
                int byte = row * 128 + kcolb;
                b[n] = *(const bf16x8*)(bb_ + (byte ^ ((row & 7) << 4)));
            }
            #pragma unroll
            for (int m = 0; m < 4; ++m)
                #pragma unroll
                for (int n = 0; n < 2; ++n)
                    acc[m][n] = __builtin_amdgcn_mfma_f32_16x16x32_bf16(a[m], b[n], acc[m][n], 0, 0, 0);
        }
        __syncthreads();
    }

    #pragma unroll
    for (int n = 0; n < 2; ++n) {
        int col = tn0 + w0 * 32 + n * 16 + r16;
        float bv = bias[col];
        #pragma unroll
        for (int m = 0; m < 4; ++m) {
            #pragma unroll
            for (int r = 0; r < 4; ++r) {
                int mm = tm0 + w1 * 64 + m * 16 + (lane >> 4) * 4 + r;
                float val = acc[m][n][r] + bv;
                if (EPI == 2) {
                    outb[(size_t)mm * N + col] = __float2bfloat16(gelu_f(val));
                } else if (EPI == 3) {
                    outf[(size_t)mm * N + col] = val + __bfloat162float(yin[(size_t)mm * N + col]);
                } else {
                    outb[((size_t)(col >> 5) * NTOK + mm) * 32 + (col & 31)] = __float2bfloat16(val);
                }
            }
        }
    }
}

// ---------------- Fused attention+proj: block = 1 window (384 thr = 6 waves, one per head).
// Phase 1 (R8-R15-validated): QK^T, softmax in-reg, P->LDS, PV -> o[4][2].
// Phase 2: att tile -> LDS At (aliases dead P buffer; 64 q-rows x 512B stride, in-row XOR
// (q&7)<<4 stays <512 for all offsets<384 -> bijective); per-wave proj slice (32 cols = its
// head), W_proj^T frags prefetched to regs (R13 pattern); EPI1 scatter y_bf16 = x + val. ----------------
__global__ __launch_bounds__(384) void attn_mp(const bf16* __restrict__ qkv,
                                               const float* __restrict__ bm,
                                               const bf16* __restrict__ pwt,   // [192 n][192 k]
                                               const float* __restrict__ pbias,
                                               const float* __restrict__ x,
                                               bf16* __restrict__ ybf)
{
    __shared__ char Pl[6][8192];    // P[q][kk] bf16, byte = q*128+kk*2 ^ ((q&7)<<4)
    __shared__ char Vt[6][4096];    // V^T[d][kk] bf16, byte = d*128+kk*2 ^ ((d&7)<<4)
    char* At = &Pl[0][0];           // phase-2 alias: 64 rows x 512B = 32768 B (< 48KB of Pl)
    const int w = blockIdx.x;
    const int h = threadIdx.x >> 6, l = threadIdx.x & 63;
    const int w49 = w * 49;
    const int wl = w & 63;
    const int cls = (((wl >> 3) == 7) ? 2 : 0) + (((wl & 7) == 7) ? 1 : 0);
    const int hi8 = (l >> 4) * 8, lo = l & 15;

    // ---- stage V^T (zero-pad kk>=49) ----
    {
        const bf16* vbase = qkv + ((size_t)(12 + h) * NTOK + w49) * 32;
        #pragma unroll
        for (int it = 0; it < 4; ++it) {
            int c = it * 64 + l;
            int kk = c >> 2, off = (c & 3) * 8;
            bf16x8 v = {};
            if (c < 196) v = *(const bf16x8*)(vbase + kk * 32 + off);
            #pragma unroll
            for (int j = 0; j < 8; ++j) {
                int d = off + j;
                int byte = (d * 128 + kk * 2) ^ ((d & 7) << 4);
                *(bf16*)(&Vt[h][0] + byte) = ((const bf16*)&v)[j];
            }
        }
    }

    // ---- QK^T ----
    const bf16* qb = qkv + ((size_t)h * NTOK + w49) * 32 + hi8;
    const bf16* kb = qkv + ((size_t)(6 + h) * NTOK + w49) * 32 + hi8;
    bf16x8 af[4], bf_[4];
    #pragma unroll
    for (int mt = 0; mt < 4; ++mt) af[mt] = *(const bf16x8*)(kb + (size_t)(mt * 16 + lo) * 32);
    #pragma unroll
    for (int ntt = 0; ntt < 4; ++ntt) bf_[ntt] = *(const bf16x8*)(qb + (size_t)(ntt * 16 + lo) * 32);
    f32x4 acc[4][4] = {};
    #pragma unroll
    for (int mt = 0; mt < 4; ++mt)
        #pragma unroll
        for (int ntt = 0; ntt < 4; ++ntt)
            acc[mt][ntt] = __builtin_amdgcn_mfma_f32_16x16x32_bf16(af[mt], bf_[ntt], acc[mt][ntt], 0, 0, 0);

    const float scale = 0.17677669529663689f;   // 32^-0.5
    const float* bmb = bm + ((size_t)(cls * 6 + h) << 4) * 256;
    #pragma unroll
    for (int mt = 0; mt < 4; ++mt)
        #pragma unroll
        for (int ntt = 0; ntt < 4; ++ntt) {
            f32x4 bmv = *(const f32x4*)(bmb + (mt * 4 + ntt) * 256 + l * 4);
            #pragma unroll
            for (int r = 0; r < 4; ++r) acc[mt][ntt][r] = acc[mt][ntt][r] * scale + bmv[r];
        }

    // ---- softmax ----
    float inv[4], mx[4];
    #pragma unroll
    for (int ntt = 0; ntt < 4; ++ntt) {
        float m_ = -1e30f;
        #pragma unroll
        for (int mt = 0; mt < 4; ++mt)
            #pragma unroll
            for (int r = 0; r < 4; ++r) m_ = fmaxf(m_, acc[mt][ntt][r]);
        m_ = fmaxf(m_, __shfl_xor(m_, 16));
        m_ = fmaxf(m_, __shfl_xor(m_, 32));
        mx[ntt] = m_;
    }
    #pragma unroll
    for (int ntt = 0; ntt < 4; ++ntt) {
        float s_ = 0.f;
        #pragma unroll
        for (int mt = 0; mt < 4; ++mt)
            #pragma unroll
            for (int r = 0; r < 4; ++r) {
                float e = __expf(acc[mt][ntt][r] - mx[ntt]);
                acc[mt][ntt][r] = e;
                s_ += e;
            }
        s_ += __shfl_xor(s_, 16);
        s_ += __shfl_xor(s_, 32);
        inv[ntt] = 1.0f / s_;
    }

    // ---- P -> LDS ----
    #pragma unroll
    for (int mt = 0; mt < 4; ++mt)
        #pragma unroll
        for (int ntt = 0; ntt < 4; ++ntt)
            #pragma unroll
            for (int rp = 0; rp < 4; rp += 2) {
                u32 pk = (u32)f2b(acc[mt][ntt][rp]) | ((u32)f2b(acc[mt][ntt][rp + 1]) << 16);
                int kk = mt * 16 + (l >> 4) * 4 + rp;
                int q  = ntt * 16 + lo;
                int byte = (q * 128 + kk * 2) ^ ((q & 7) << 4);
                *(u32*)(&Pl[h][0] + byte) = pk;
            }

    // ---- PV ----
    f32x4 o[4][2] = {};
    #pragma unroll
    for (int ks = 0; ks < 2; ++ks) {
        int kb_ = (ks * 32 + hi8) * 2;
        bf16x8 pa[4], vb[2];
        #pragma unroll
        for (int qt = 0; qt < 4; ++qt) {
            int row = qt * 16 + lo;
            pa[qt] = *(const bf16x8*)(&Pl[h][0] + ((row * 128 + kb_) ^ ((row & 7) << 4)));
        }
        #pragma unroll
        for (int dt = 0; dt < 2; ++dt) {
            int row = dt * 16 + lo;
            vb[dt] = *(const bf16x8*)(&Vt[h][0] + ((row * 128 + kb_) ^ ((row & 7) << 4)));
        }
        #pragma unroll
        for (int qt = 0; qt < 4; ++qt)
            #pragma unroll
            for (int dt = 0; dt < 2; ++dt)
                o[qt][dt] = __builtin_amdgcn_mfma_f32_16x16x32_bf16(pa[qt], vb[dt], o[qt][dt], 0, 0, 0);
    }

    // ==== phase 2: proj ====
    __syncthreads();   // all PV reads of Pl done before At overwrites it
    #pragma unroll
    for (int qt = 0; qt < 4; ++qt)
        #pragma unroll
        for (int r = 0; r < 4; ++r) {
            int qrow = (l >> 4) * 4 + r;
            float iv = __shfl(inv[qt], qrow);
            int q = qt * 16 + qrow;
            #pragma unroll
            for (int dt = 0; dt < 2; ++dt) {
                int d = h * 32 + dt * 16 + lo;
                int byte = q * 512 + ((d * 2) ^ ((q & 7) << 4));
                *(bf16*)(At + byte) = __float2bfloat16(o[qt][dt][r] * iv);
            }
        }
    // prefetch W_proj^T frags for this wave's 32 output cols (n = h*32 + {0..31})
    bf16x8 wp[6][2];
    {
        const bf16* wb0 = pwt + (size_t)(h * 32 + lo) * 192 + hi8;
        const bf16* wb1 = wb0 + (size_t)16 * 192;
        #pragma unroll
        for (int t6 = 0; t6 < 6; ++t6) {
            wp[t6][0] = *(const bf16x8*)(wb0 + t6 * 32);
            wp[t6][1] = *(const bf16x8*)(wb1 + t6 * 32);
        }
    }
    float pb0 = pbias[h * 32 + lo], pb1 = pbias[h * 32 + 16 + lo];
    __syncthreads();   // At complete

    f32x4 acc2[4][2] = {};
    #pragma unroll
    for (int t6 = 0; t6 < 6; ++t6) {
        int k2b = (t6 * 32 + hi8) * 2;
        bf16x8 am[4];
        #pragma unroll
        for (int mt = 0; mt < 4; ++mt) {
            int q = mt * 16 + lo;
            am[mt] = *(const bf16x8*)(At + q * 512 + (k2b ^ ((q & 7) << 4)));
        }
        #pragma unroll
        for (int mt = 0; mt < 4; ++mt)
            #pragma unroll
            for (int nf = 0; nf < 2; ++nf)
                acc2[mt][nf] = __builtin_amdgcn_mfma_f32_16x16x32_bf16(am[mt], wp[t6][nf], acc2[mt][nf], 0, 0, 0);
    }

    // ---- scatter epilogue: y_bf16 = x + proj(att) (window-reverse + roll(+3,+3)) ----
    const int b_ = w >> 6, hb = wl >> 3, wb2 = wl & 7;
    #pragma unroll
    for (int mt = 0; mt < 4; ++mt) {
        #pragma unroll
        for (int r = 0; r < 4; ++r) {
            int q = mt * 16 + (l >> 4) * 4 + r;
            if (q < 49) {
                int i = q / 7, j = q % 7;
                int oh = hb * 7 + i + 3; if (oh >= 56) oh -= 56;
                int ow = wb2 * 7 + j + 3; if (ow >= 56) ow -= 56;
                size_t dst = ((size_t)(b_ * 56 + oh) * 56 + ow) * CC;
                int n0 = h * 32 + lo;
                ybf[dst + n0]      = __float2bfloat16(x[dst + n0]      + acc2[mt][0][r] + pb0);
                ybf[dst + n0 + 16] = __float2bfloat16(x[dst + n0 + 16] + acc2[mt][1][r] + pb1);
            }
        }
    }
}

// ---------------- launch ----------------
extern "C" void kernel_launch(void* const* d_in, const int* in_sizes, int n_in,
                              void* d_out, int out_size, void* d_ws, size_t ws_size,
                              hipStream_t stream) {
    const float* x      = (const float*)d_in[0];
    const float* n1g    = (const float*)d_in[1];
    const float* n1b    = (const float*)d_in[2];
    const float* qkv_w  = (const float*)d_in[3];
    const float* qkv_b  = (const float*)d_in[4];
    const float* proj_w = (const float*)d_in[5];
    const float* proj_b = (const float*)d_in[6];
    const float* btab   = (const float*)d_in[7];
    const float* n2g    = (const float*)d_in[8];
    const float* n2b    = (const float*)d_in[9];
    const float* fc1_w  = (const float*)d_in[10];
    const float* fc1_b  = (const float*)d_in[11];
    const float* fc2_w  = (const float*)d_in[12];
    const float* fc2_b  = (const float*)d_in[13];

    char* ws = (char*)d_ws;
    //  xw   [0, 38535168)            bf16 [100352][192]  (LN1 out; reused as LN2 out m)
    //  qkv  [38535168, 154140672)    bf16 head-planar [3][6][NTOK][32]
    //        (MLP phase: hid bf16 [100352][768] reuses [38535168, 192675840))
    //  ybf  [192675840, 231211008)   bf16 y residual — PAST hidb's end (R16 bug: overlapped)
    //  wt   [231211008, 232095744)   transposed bf16 weights
    //  bm   [232095744, 232488960)   biasmask f32 [4][6][16][256]
    //  final fp32 y+mlp written once to d_out by fc2.
    const size_t XW_OFF  = 0;
    const size_t QKV_OFF = 38535168;
    const size_t YB_OFF  = 192675840;
    const size_t WT_OFF  = 231211008;
    const size_t BM_OFF  = 232095744;
    if (ws_size < 232488960ull) return;   // diagnostic: zeros signature (absmax ~5.59)

    bf16* xw   = (bf16*)(ws + XW_OFF);
    bf16* mbuf = (bf16*)(ws + XW_OFF);
    bf16* qkvb = (bf16*)(ws + QKV_OFF);
    bf16* hidb = (bf16*)(ws + QKV_OFF);      // MLP phase reuse [38535168, 192675840)
    bf16* ybf  = (bf16*)(ws + YB_OFF);
    float* yout = (float*)d_out;
    bf16* wt   = (bf16*)(ws + WT_OFF);
    float* bmt = (float*)(ws + BM_OFF);
    bf16* qkv_wT  = wt;                       // [576][192]
    bf16* proj_wT = wt + 110592;              // [192][192]
    bf16* fc1_wT  = wt + 147456;              // [768][192]
    bf16* fc2_wT  = wt + 294912;              // [192][768]

    prep_k<<<dim3(2112), 256, 0, stream>>>(qkv_w, proj_w, fc1_w, fc2_w, btab,
                                           qkv_wT, proj_wT, fc1_wT, fc2_wT, bmt);

    ln_k<float, true><<<NTOK / 4, 256, 0, stream>>>(x, n1g, n1b, xw);

    gemm_t<4><<<dim3(9, 392), 512, 0, stream>>>(
        xw, qkv_wT, qkv_b, 192, 576, qkvb, nullptr, nullptr);

    attn_mp<<<dim3(2048), 384, 0, stream>>>(qkvb, bmt, proj_wT, proj_b, x, ybf);

    ln_k<bf16, false><<<NTOK / 4, 256, 0, stream>>>(ybf, n2g, n2b, mbuf);

    gemm_t<2><<<dim3(12, 392), 512, 0, stream>>>(
        mbuf, fc1_wT, fc1_b, 192, 768, hidb, nullptr, nullptr);
    gemm_t<3><<<dim3(3, 392), 512, 0, stream>>>(
        hidb, fc2_wT, fc2_b, 768, 192, nullptr, yout, ybf);
}